// Round 5
// baseline (44.913 us; speedup 1.0000x reference)
//
#include <hip/hip_runtime.h>

// QProduct: out_real/out_imag[b,s, j0*1024 + j1*32 + j2] =
//   ((1+1i) * h0[j0] * h1[j1] * h2[j2]) split into real/imag.
// B=8, S=128, d=32. Output: two (B,S,32768) fp32 tensors concatenated.
// Memory-bound on 268 MB of streaming writes.
// This variant: each block = ONE plane x TWO consecutive bs chunks
// (256 KB purely sequential write stream) to halve concurrent streams/CU.

#define BS_TOTAL 1024           // B*S
#define D 32
#define OUT_PER_BS 32768        // 32*32*32
#define IMAG_OFF ((long long)BS_TOTAL * OUT_PER_BS)

typedef float f32x4 __attribute__((ext_vector_type(4)));

__global__ __launch_bounds__(512) void qproduct_kernel(
    const float* __restrict__ h0r, const float* __restrict__ h0i,
    const float* __restrict__ h1r, const float* __restrict__ h1i,
    const float* __restrict__ h2r, const float* __restrict__ h2i,
    float* __restrict__ out)
{
    const int c     = blockIdx.x;        // 0..1023
    const int plane = c >> 9;            // 0 = real, 1 = imag
    const int bs0   = (c & 511) << 1;    // first of 2 consecutive bs chunks

    const int tid  = threadIdx.x;        // 0..511
    const int lane = tid & 255;          // position within a 4 KB row pair
    const int j0h  = tid >> 8;           // j0 parity (0/1)

    const int j1  = lane >> 3;           // 0..31
    const int j2b = (lane & 7) << 2;     // 0,4,...,28

    __shared__ float s_h0r[2][D];
    __shared__ float s_h0i[2][D];

    if (tid < 2 * D) {
        const int w = tid >> 5;          // which bs of the pair
        const int e = tid & 31;
        s_h0r[w][e] = h0r[(bs0 + w) * D + e];
        s_h0i[w][e] = h0i[(bs0 + w) * D + e];
    }
    __syncthreads();

    #pragma unroll
    for (int w = 0; w < 2; ++w) {
        const int bs   = bs0 + w;
        const int base = bs * D;
        const float b1r = h1r[base + j1];
        const float b1i = h1i[base + j1];
        const f32x4 c2r = *reinterpret_cast<const f32x4*>(h2r + base + j2b);
        const f32x4 c2i = *reinterpret_cast<const f32x4*>(h2i + base + j2b);

        float* __restrict__ outP = out + plane * IMAG_OFF
                                 + (long long)bs * OUT_PER_BS + (lane << 2);

        #pragma unroll
        for (int it = 0; it < 16; ++it) {
            const int j0 = (it << 1) + j0h;
            const float a0r = s_h0r[w][j0];
            const float a0i = s_h0i[w][j0];
            // t1 = (1 + 1i) * h0[j0]  (reference inits BOTH tp accumulators to 1)
            const float t1r = a0r - a0i;
            const float t1i = a0r + a0i;
            const float t2r = t1r * b1r - t1i * b1i;
            const float t2i = t1r * b1i + t1i * b1r;
            const f32x4 v = (plane == 0) ? (t2r * c2r - t2i * c2i)
                                         : (t2r * c2i + t2i * c2r);
            *reinterpret_cast<f32x4*>(outP + j0 * 1024) = v;
        }
    }
}

extern "C" void kernel_launch(void* const* d_in, const int* in_sizes, int n_in,
                              void* d_out, int out_size, void* d_ws, size_t ws_size,
                              hipStream_t stream) {
    const float* h0r = (const float*)d_in[0];
    const float* h0i = (const float*)d_in[1];
    const float* h1r = (const float*)d_in[2];
    const float* h1i = (const float*)d_in[3];
    const float* h2r = (const float*)d_in[4];
    const float* h2i = (const float*)d_in[5];
    float* out = (float*)d_out;

    qproduct_kernel<<<BS_TOTAL, 512, 0, stream>>>(h0r, h0i, h1r, h1i, h2r, h2i, out);
}